// Round 1
// baseline (83.112 us; speedup 1.0000x reference)
//
#include <hip/hip_runtime.h>

#define BB 8
#define GG 8
#define HH 4
#define KK 8192
#define DD 128
#define RR 32
#define KPB 256     // keys per block
#define THREADS 256

__global__ __launch_bounds__(THREADS) void lowrank_scores(
    const float* __restrict__ query,
    const float* __restrict__ key,
    const float* __restrict__ weight,
    float* __restrict__ out)
{
    __shared__ float w_lds[DD * RR];   // 16 KB, layout [d][r]
    __shared__ float qproj[HH][RR];    // 512 B
    __shared__ float u_lds[HH][DD];    // 2 KB

    const int bpbg = KK / KPB;         // blocks per (b,g) = 32
    const int bg   = blockIdx.x / bpbg;
    const int kblk = blockIdx.x % bpbg;
    const int g    = bg & (GG - 1);
    const int tid  = threadIdx.x;

    // ---- stage W[g] into LDS (coalesced float4) ----
    const float4* wg = (const float4*)(weight + (size_t)g * DD * RR);
    float4* wl = (float4*)w_lds;
    for (int i = tid; i < DD * RR / 4; i += THREADS) wl[i] = wg[i];
    __syncthreads();

    // ---- qproj[h][r] = sum_d q[b,g,h,d] * w[d][r] ----
    if (tid < HH * RR) {
        const int h = tid >> 5, r = tid & (RR - 1);
        const float* qp = query + ((size_t)bg * HH + h) * DD;
        float s = 0.f;
        #pragma unroll 8
        for (int d = 0; d < DD; ++d) s += qp[d] * w_lds[d * RR + r];
        qproj[h][r] = s;
    }
    __syncthreads();

    // ---- u[h][d] = sum_r qproj[h][r] * w[d][r]  (rotated r to avoid
    //      the 32-way bank conflict of stride-32 column reads) ----
    for (int idx = tid; idx < HH * DD; idx += THREADS) {
        const int h = idx >> 7, d = idx & (DD - 1);
        float s = 0.f;
        #pragma unroll
        for (int rr = 0; rr < RR; ++rr) {
            const int r = (rr + d) & (RR - 1);
            s += qproj[h][r] * w_lds[d * RR + r];
        }
        u_lds[h][d] = s;
    }
    __syncthreads();

    // ---- main loop: out[h][k] = scale * dot(u[h], key[k]) ----
    const int lane = tid & 63;
    const int wave = tid >> 6;
    const int dc   = lane & 31;   // which float4 chunk of D
    const int kh   = lane >> 5;   // which key of this wave's pair
    const float4 u0 = *(const float4*)&u_lds[0][dc * 4];
    const float4 u1 = *(const float4*)&u_lds[1][dc * 4];
    const float4 u2 = *(const float4*)&u_lds[2][dc * 4];
    const float4 u3 = *(const float4*)&u_lds[3][dc * 4];

    const float* keyb = key + (size_t)bg * KK * DD;
    float* outb = out + (size_t)bg * HH * KK;
    const float scale = 0.08838834764831845f;   // 128^-0.5
    const int kbase = kblk * KPB;

    for (int it = 0; it < KPB / 8; ++it) {
        const int k = kbase + it * 8 + wave * 2 + kh;
        const float4 kv = *(const float4*)(keyb + (size_t)k * DD + dc * 4);
        float a0 = kv.x * u0.x + kv.y * u0.y + kv.z * u0.z + kv.w * u0.w;
        float a1 = kv.x * u1.x + kv.y * u1.y + kv.z * u1.z + kv.w * u1.w;
        float a2 = kv.x * u2.x + kv.y * u2.y + kv.z * u2.z + kv.w * u2.w;
        float a3 = kv.x * u3.x + kv.y * u3.y + kv.z * u3.z + kv.w * u3.w;
        #pragma unroll
        for (int off = 16; off >= 1; off >>= 1) {
            a0 += __shfl_xor(a0, off);
            a1 += __shfl_xor(a1, off);
            a2 += __shfl_xor(a2, off);
            a3 += __shfl_xor(a3, off);
        }
        if (dc == 0) {
            outb[(size_t)0 * KK + k] = a0 * scale;
            outb[(size_t)1 * KK + k] = a1 * scale;
            outb[(size_t)2 * KK + k] = a2 * scale;
            outb[(size_t)3 * KK + k] = a3 * scale;
        }
    }
}

extern "C" void kernel_launch(void* const* d_in, const int* in_sizes, int n_in,
                              void* d_out, int out_size, void* d_ws, size_t ws_size,
                              hipStream_t stream) {
    const float* query  = (const float*)d_in[0];
    const float* key    = (const float*)d_in[1];
    const float* weight = (const float*)d_in[2];
    float* out = (float*)d_out;

    const int grid = BB * GG * (KK / KPB);   // 2048 blocks
    lowrank_scores<<<dim3(grid), dim3(THREADS), 0, stream>>>(query, key, weight, out);
}

// Round 2
// 74.004 us; speedup vs baseline: 1.1231x; 1.1231x over previous
//
#include <hip/hip_runtime.h>

#define BB 8
#define GG 8
#define HH 4
#define KK 8192
#define DD 128
#define RR 32
#define KPB 256     // keys per block
#define THREADS 256

#define DOT4(v, u) ((v).x * (u).x + (v).y * (u).y + (v).z * (u).z + (v).w * (u).w)

__global__ __launch_bounds__(THREADS) void lowrank_scores(
    const float* __restrict__ query,
    const float* __restrict__ key,
    const float* __restrict__ weight,
    float* __restrict__ out)
{
    __shared__ float w_lds[DD * RR];   // 16 KB, layout [d][r]
    __shared__ float qproj[HH][RR];    // 512 B
    __shared__ float u_lds[HH][DD];    // 2 KB

    const int bpbg = KK / KPB;         // blocks per (b,g) = 32
    const int bg   = blockIdx.x / bpbg;
    const int kblk = blockIdx.x % bpbg;
    const int g    = bg & (GG - 1);
    const int tid  = threadIdx.x;

    // ---- stage W[g] into LDS (coalesced float4) ----
    const float4* wg = (const float4*)(weight + (size_t)g * DD * RR);
    float4* wl = (float4*)w_lds;
    for (int i = tid; i < DD * RR / 4; i += THREADS) wl[i] = wg[i];
    __syncthreads();

    // ---- qproj[h][r] = sum_d q[b,g,h,d] * w[d][r] ----
    if (tid < HH * RR) {
        const int h = tid >> 5, r = tid & (RR - 1);
        const float* qp = query + ((size_t)bg * HH + h) * DD;
        float s = 0.f;
        #pragma unroll 8
        for (int d = 0; d < DD; ++d) s += qp[d] * w_lds[d * RR + r];
        qproj[h][r] = s;
    }
    __syncthreads();

    // ---- u[h][d] = sum_r qproj[h][r] * w[d][r]  (rotated r to avoid
    //      the 32-way bank conflict of stride-32 column reads) ----
    for (int idx = tid; idx < HH * DD; idx += THREADS) {
        const int h = idx >> 7, d = idx & (DD - 1);
        float s = 0.f;
        #pragma unroll
        for (int rr = 0; rr < RR; ++rr) {
            const int r = (rr + d) & (RR - 1);
            s += qproj[h][r] * w_lds[d * RR + r];
        }
        u_lds[h][d] = s;
    }
    __syncthreads();

    // ---- main loop: out[h][k] = scale * dot(u[h], key[k]) ----
    // lanes 0-31 handle key k, lanes 32-63 key k+1; dc = float4 chunk of D.
    // Unrolled x4 with batched loads: 4 x 1KB wave-loads in flight, then 4
    // independent FMA+butterfly groups (16-way ILP on the shuffle chain).
    const int lane = tid & 63;
    const int wave = tid >> 6;
    const int dc   = lane & 31;
    const int kh   = lane >> 5;
    const float4 u0 = *(const float4*)&u_lds[0][dc * 4];
    const float4 u1 = *(const float4*)&u_lds[1][dc * 4];
    const float4 u2 = *(const float4*)&u_lds[2][dc * 4];
    const float4 u3 = *(const float4*)&u_lds[3][dc * 4];

    const float* keyb = key + (size_t)bg * KK * DD;
    float* outb = out + (size_t)bg * HH * KK;
    const float scale = 0.08838834764831845f;   // 128^-0.5
    const int kfirst = kblk * KPB + wave * 2 + kh;   // this wave-half's first key
    const float* kp = keyb + (size_t)kfirst * DD + dc * 4;

    for (int it = 0; it < KPB / 8; it += 4) {
        const float* p = kp + (size_t)it * (8 * DD);
        const float4 kv0 = *(const float4*)(p);
        const float4 kv1 = *(const float4*)(p + 1 * 8 * DD);
        const float4 kv2 = *(const float4*)(p + 2 * 8 * DD);
        const float4 kv3 = *(const float4*)(p + 3 * 8 * DD);

        float a00 = DOT4(kv0, u0), a01 = DOT4(kv0, u1), a02 = DOT4(kv0, u2), a03 = DOT4(kv0, u3);
        float a10 = DOT4(kv1, u0), a11 = DOT4(kv1, u1), a12 = DOT4(kv1, u2), a13 = DOT4(kv1, u3);
        float a20 = DOT4(kv2, u0), a21 = DOT4(kv2, u1), a22 = DOT4(kv2, u2), a23 = DOT4(kv2, u3);
        float a30 = DOT4(kv3, u0), a31 = DOT4(kv3, u1), a32 = DOT4(kv3, u2), a33 = DOT4(kv3, u3);

        #pragma unroll
        for (int off = 16; off >= 1; off >>= 1) {
            a00 += __shfl_xor(a00, off); a10 += __shfl_xor(a10, off);
            a20 += __shfl_xor(a20, off); a30 += __shfl_xor(a30, off);
            a01 += __shfl_xor(a01, off); a11 += __shfl_xor(a11, off);
            a21 += __shfl_xor(a21, off); a31 += __shfl_xor(a31, off);
            a02 += __shfl_xor(a02, off); a12 += __shfl_xor(a12, off);
            a22 += __shfl_xor(a22, off); a32 += __shfl_xor(a32, off);
            a03 += __shfl_xor(a03, off); a13 += __shfl_xor(a13, off);
            a23 += __shfl_xor(a23, off); a33 += __shfl_xor(a33, off);
        }

        if (dc == 0) {
            const int k = kfirst + it * 8;
            outb[(size_t)0 * KK + k     ] = a00 * scale;
            outb[(size_t)0 * KK + k +  8] = a10 * scale;
            outb[(size_t)0 * KK + k + 16] = a20 * scale;
            outb[(size_t)0 * KK + k + 24] = a30 * scale;
            outb[(size_t)1 * KK + k     ] = a01 * scale;
            outb[(size_t)1 * KK + k +  8] = a11 * scale;
            outb[(size_t)1 * KK + k + 16] = a21 * scale;
            outb[(size_t)1 * KK + k + 24] = a31 * scale;
            outb[(size_t)2 * KK + k     ] = a02 * scale;
            outb[(size_t)2 * KK + k +  8] = a12 * scale;
            outb[(size_t)2 * KK + k + 16] = a22 * scale;
            outb[(size_t)2 * KK + k + 24] = a32 * scale;
            outb[(size_t)3 * KK + k     ] = a03 * scale;
            outb[(size_t)3 * KK + k +  8] = a13 * scale;
            outb[(size_t)3 * KK + k + 16] = a23 * scale;
            outb[(size_t)3 * KK + k + 24] = a33 * scale;
        }
    }
}

extern "C" void kernel_launch(void* const* d_in, const int* in_sizes, int n_in,
                              void* d_out, int out_size, void* d_ws, size_t ws_size,
                              hipStream_t stream) {
    const float* query  = (const float*)d_in[0];
    const float* key    = (const float*)d_in[1];
    const float* weight = (const float*)d_in[2];
    float* out = (float*)d_out;

    const int grid = BB * GG * (KK / KPB);   // 2048 blocks
    lowrank_scores<<<dim3(grid), dim3(THREADS), 0, stream>>>(query, key, weight, out);
}